// Round 1
// baseline (1447.610 us; speedup 1.0000x reference)
//
#include <hip/hip_runtime.h>

typedef float  f32x4 __attribute__((ext_vector_type(4)));
typedef short  s16x8 __attribute__((ext_vector_type(8)));
typedef unsigned short ushort_t;

#define GAS __attribute__((address_space(1)))
#define LAS __attribute__((address_space(3)))

constexpr int M = 8192;       // B*S
constexpr int N = 16384;      // D_OUT
constexpr int K = 4096;       // D_IN
constexpr long long NX = (long long)M * K;   // 33,554,432
constexpr long long NW = (long long)N * K;   // 67,108,864
constexpr int NPART = 2048;

// ---------------- reductions ----------------

__global__ void reduce_absmax_kernel(const float* __restrict__ x,
                                     unsigned* __restrict__ gmax, int n4) {
  float m = 0.f;
  int stride = gridDim.x * blockDim.x;
  for (int i = blockIdx.x * blockDim.x + threadIdx.x; i < n4; i += stride) {
    f32x4 v = *(const f32x4*)(x + (size_t)i * 4);
    m = fmaxf(m, fmaxf(fmaxf(fabsf(v[0]), fabsf(v[1])),
                       fmaxf(fabsf(v[2]), fabsf(v[3]))));
  }
#pragma unroll
  for (int off = 32; off > 0; off >>= 1) m = fmaxf(m, __shfl_down(m, off));
  __shared__ float sm[4];
  int lane = threadIdx.x & 63, wid = threadIdx.x >> 6;
  if (lane == 0) sm[wid] = m;
  __syncthreads();
  if (threadIdx.x == 0) {
    m = fmaxf(fmaxf(sm[0], sm[1]), fmaxf(sm[2], sm[3]));
    atomicMax(gmax, __float_as_uint(m));  // |x| >= 0: bit-order == float-order
  }
}

__global__ void reduce_abssum_kernel(const float* __restrict__ w,
                                     float* __restrict__ partials, int n4) {
  float s = 0.f;
  int stride = gridDim.x * blockDim.x;
  for (int i = blockIdx.x * blockDim.x + threadIdx.x; i < n4; i += stride) {
    f32x4 v = *(const f32x4*)(w + (size_t)i * 4);
    s += fabsf(v[0]) + fabsf(v[1]) + fabsf(v[2]) + fabsf(v[3]);
  }
#pragma unroll
  for (int off = 32; off > 0; off >>= 1) s += __shfl_down(s, off);
  __shared__ float sm[4];
  int lane = threadIdx.x & 63, wid = threadIdx.x >> 6;
  if (lane == 0) sm[wid] = s;
  __syncthreads();
  if (threadIdx.x == 0) partials[blockIdx.x] = (sm[0] + sm[1]) + (sm[2] + sm[3]);
}

__global__ void finalize_kernel(const unsigned* __restrict__ gbits,
                                const float* __restrict__ partials,
                                float* __restrict__ params) {
  __shared__ double sd[256];
  double s = 0.0;
  for (int i = threadIdx.x; i < NPART; i += 256) s += (double)partials[i];
  sd[threadIdx.x] = s;
  __syncthreads();
  for (int h = 128; h > 0; h >>= 1) {
    if (threadIdx.x < h) sd[threadIdx.x] += sd[threadIdx.x + h];
    __syncthreads();
  }
  if (threadIdx.x == 0) {
    float beta  = fmaxf((float)(sd[0] / (double)NW), 1e-5f);
    float gamma = fmaxf(__uint_as_float(gbits[0]), 1e-5f);
    params[0] = 128.0f / gamma;          // activation scale (q/gamma)
    params[1] = beta;                    // weight divisor
    params[2] = beta * gamma / 128.0f;   // output rescale
  }
}

// ---------------- quantization ----------------

__global__ void quant_x_kernel(const float* __restrict__ x,
                               ushort_t* __restrict__ xq,
                               const float* __restrict__ params, int n8) {
  float s = params[0];
  int stride = gridDim.x * blockDim.x;
  for (int i = blockIdx.x * blockDim.x + threadIdx.x; i < n8; i += stride) {
    const float* p = x + (size_t)i * 8;
    f32x4 v0 = *(const f32x4*)p;
    f32x4 v1 = *(const f32x4*)(p + 4);
    s16x8 o;
#pragma unroll
    for (int k = 0; k < 4; ++k) {
      float t = fminf(fmaxf(rintf(v0[k] * s), -128.f), 127.f);
      o[k] = (short)(__float_as_uint(t) >> 16);   // exact bf16 (|int| <= 128)
      float u = fminf(fmaxf(rintf(v1[k] * s), -128.f), 127.f);
      o[k + 4] = (short)(__float_as_uint(u) >> 16);
    }
    *(s16x8*)(xq + (size_t)i * 8) = o;
  }
}

__global__ void quant_w_kernel(const float* __restrict__ w,
                               ushort_t* __restrict__ wq,
                               const float* __restrict__ params, int n8) {
  float beta = params[1];
  int stride = gridDim.x * blockDim.x;
  for (int i = blockIdx.x * blockDim.x + threadIdx.x; i < n8; i += stride) {
    const float* p = w + (size_t)i * 8;
    f32x4 v0 = *(const f32x4*)p;
    f32x4 v1 = *(const f32x4*)(p + 4);
    s16x8 o;
#pragma unroll
    for (int k = 0; k < 4; ++k) {
      // round_clip(|w|/beta, -1, 1): nonneg -> {0,1}; IEEE div matches ref rounding
      float r0 = rintf(fabsf(v0[k]) / beta);
      o[k] = (r0 >= 1.0f) ? (short)0x3F80 : (short)0;   // bf16 1.0 or 0.0
      float r1 = rintf(fabsf(v1[k]) / beta);
      o[k + 4] = (r1 >= 1.0f) ? (short)0x3F80 : (short)0;
    }
    *(s16x8*)(wq + (size_t)i * 8) = o;
  }
}

// ---------------- GEMM (m97-structure: 128x128 tile, 16x16x32 bf16 MFMA) ----------------
// C[m][n] = sum_k A[m][k] * B[n][k]  (B stored row-major [N][K] == B^T input)

__global__ __launch_bounds__(256) void gemm_kernel(
    const ushort_t* __restrict__ A,   // xq bf16 [M][K]
    const ushort_t* __restrict__ B,   // wq bf16 [N][K]
    float* __restrict__ C,            // [M][N] fp32
    const float* __restrict__ params) {
  __shared__ ushort_t As[128 * 32];
  __shared__ ushort_t Bs[128 * 32];

  const int tid  = threadIdx.x;
  const int lane = tid & 63, wid = tid >> 6;
  const int wr = wid >> 1, wc = wid & 1;          // 2x2 waves, each 64x64
  const int r16 = lane & 15, q4 = lane >> 4;
  const int m0 = blockIdx.y * 128, n0 = blockIdx.x * 128;
  const float sc = params[2];

  // staging: two 16B rounds per tile per operand; LDS dest linear in thread order
  const int i0 = tid, i1 = 256 + tid;
  const ushort_t* ga0 = A + (size_t)(m0 + (i0 >> 2)) * K + (i0 & 3) * 8;
  const ushort_t* ga1 = A + (size_t)(m0 + (i1 >> 2)) * K + (i1 & 3) * 8;
  const ushort_t* gb0 = B + (size_t)(n0 + (i0 >> 2)) * K + (i0 & 3) * 8;
  const ushort_t* gb1 = B + (size_t)(n0 + (i1 >> 2)) * K + (i1 & 3) * 8;
  ushort_t* la0 = &As[i0 * 8];
  ushort_t* la1 = &As[i1 * 8];
  ushort_t* lb0 = &Bs[i0 * 8];
  ushort_t* lb1 = &Bs[i1 * 8];

  int aoff[4], boff[4];
#pragma unroll
  for (int i = 0; i < 4; ++i) {
    aoff[i] = (wr * 64 + i * 16 + r16) * 32 + q4 * 8;
    boff[i] = (wc * 64 + i * 16 + r16) * 32 + q4 * 8;
  }

  f32x4 acc[4][4] = {};

  for (int kt = 0; kt < K / 32; ++kt) {
    const int ko = kt * 32;
    __builtin_amdgcn_global_load_lds((const GAS void*)(ga0 + ko), (LAS void*)la0, 16, 0, 0);
    __builtin_amdgcn_global_load_lds((const GAS void*)(ga1 + ko), (LAS void*)la1, 16, 0, 0);
    __builtin_amdgcn_global_load_lds((const GAS void*)(gb0 + ko), (LAS void*)lb0, 16, 0, 0);
    __builtin_amdgcn_global_load_lds((const GAS void*)(gb1 + ko), (LAS void*)lb1, 16, 0, 0);
    __syncthreads();   // compiler emits vmcnt(0) drain before barrier

    s16x8 af[4], bf[4];
#pragma unroll
    for (int i = 0; i < 4; ++i) af[i] = *(const s16x8*)&As[aoff[i]];
#pragma unroll
    for (int j = 0; j < 4; ++j) bf[j] = *(const s16x8*)&Bs[boff[j]];
#pragma unroll
    for (int i = 0; i < 4; ++i)
#pragma unroll
      for (int j = 0; j < 4; ++j)
        acc[i][j] = __builtin_amdgcn_mfma_f32_16x16x32_bf16(af[i], bf[j], acc[i][j], 0, 0, 0);
    __syncthreads();
  }

  // C/D layout (m89-verified): col = lane&15, row = (lane>>4)*4 + reg
  const int crow = m0 + wr * 64 + q4 * 4;
  const int ccol = n0 + wc * 64 + r16;
#pragma unroll
  for (int i = 0; i < 4; ++i)
#pragma unroll
    for (int j = 0; j < 4; ++j)
#pragma unroll
      for (int r = 0; r < 4; ++r)
        C[(size_t)(crow + i * 16 + r) * N + (ccol + j * 16)] = acc[i][j][r] * sc;
}

// ---------------- launch ----------------

extern "C" void kernel_launch(void* const* d_in, const int* in_sizes, int n_in,
                              void* d_out, int out_size, void* d_ws, size_t ws_size,
                              hipStream_t stream) {
  const float* x = (const float*)d_in[0];
  const float* w = (const float*)d_in[1];
  float* out = (float*)d_out;
  char* ws = (char*)d_ws;

  unsigned* gamma_bits = (unsigned*)ws;            // 4 B
  float*    params     = (float*)(ws + 16);        // 3 floats
  float*    partials   = (float*)(ws + 256);       // 2048 floats
  ushort_t* xq = (ushort_t*)(ws + 16384);                         // 67,108,864 B
  ushort_t* wq = (ushort_t*)(ws + 16384 + (size_t)NX * 2);        // 134,217,728 B

  hipMemsetAsync(ws, 0, 256, stream);  // zero gamma accumulator each call

  reduce_absmax_kernel<<<NPART, 256, 0, stream>>>(x, gamma_bits, (int)(NX / 4));
  reduce_abssum_kernel<<<NPART, 256, 0, stream>>>(w, partials, (int)(NW / 4));
  finalize_kernel<<<1, 256, 0, stream>>>(gamma_bits, partials, params);
  quant_x_kernel<<<2048, 256, 0, stream>>>(x, xq, params, (int)(NX / 8));
  quant_w_kernel<<<2048, 256, 0, stream>>>(w, wq, params, (int)(NW / 8));

  dim3 grid(N / 128, M / 128);
  gemm_kernel<<<grid, 256, 0, stream>>>(xq, wq, out, params);
}

// Round 2
// 863.359 us; speedup vs baseline: 1.6767x; 1.6767x over previous
//
#include <hip/hip_runtime.h>

typedef float f32x4 __attribute__((ext_vector_type(4)));
typedef int   i32x4 __attribute__((ext_vector_type(4)));
typedef char  s8x16 __attribute__((ext_vector_type(16)));

#define GAS __attribute__((address_space(1)))
#define LAS __attribute__((address_space(3)))

constexpr int M = 8192;       // B*S
constexpr int N = 16384;      // D_OUT
constexpr int K = 4096;       // D_IN
constexpr long long NX = (long long)M * K;   // 33,554,432
constexpr long long NW = (long long)N * K;   // 67,108,864
constexpr int NPART = 2048;

// ---------------- reductions ----------------

__global__ void reduce_absmax_kernel(const float* __restrict__ x,
                                     unsigned* __restrict__ gmax, int n4) {
  float m = 0.f;
  int stride = gridDim.x * blockDim.x;
  for (int i = blockIdx.x * blockDim.x + threadIdx.x; i < n4; i += stride) {
    f32x4 v = *(const f32x4*)(x + (size_t)i * 4);
    m = fmaxf(m, fmaxf(fmaxf(fabsf(v[0]), fabsf(v[1])),
                       fmaxf(fabsf(v[2]), fabsf(v[3]))));
  }
#pragma unroll
  for (int off = 32; off > 0; off >>= 1) m = fmaxf(m, __shfl_down(m, off));
  __shared__ float sm[4];
  int lane = threadIdx.x & 63, wid = threadIdx.x >> 6;
  if (lane == 0) sm[wid] = m;
  __syncthreads();
  if (threadIdx.x == 0) {
    m = fmaxf(fmaxf(sm[0], sm[1]), fmaxf(sm[2], sm[3]));
    atomicMax(gmax, __float_as_uint(m));  // |x| >= 0: bit-order == float-order
  }
}

__global__ void reduce_abssum_kernel(const float* __restrict__ w,
                                     float* __restrict__ partials, int n4) {
  float s = 0.f;
  int stride = gridDim.x * blockDim.x;
  for (int i = blockIdx.x * blockDim.x + threadIdx.x; i < n4; i += stride) {
    f32x4 v = *(const f32x4*)(w + (size_t)i * 4);
    s += fabsf(v[0]) + fabsf(v[1]) + fabsf(v[2]) + fabsf(v[3]);
  }
#pragma unroll
  for (int off = 32; off > 0; off >>= 1) s += __shfl_down(s, off);
  __shared__ float sm[4];
  int lane = threadIdx.x & 63, wid = threadIdx.x >> 6;
  if (lane == 0) sm[wid] = s;
  __syncthreads();
  if (threadIdx.x == 0) partials[blockIdx.x] = (sm[0] + sm[1]) + (sm[2] + sm[3]);
}

__global__ void finalize_kernel(const unsigned* __restrict__ gbits,
                                const float* __restrict__ partials,
                                float* __restrict__ params) {
  __shared__ double sd[256];
  double s = 0.0;
  for (int i = threadIdx.x; i < NPART; i += 256) s += (double)partials[i];
  sd[threadIdx.x] = s;
  __syncthreads();
  for (int h = 128; h > 0; h >>= 1) {
    if (threadIdx.x < h) sd[threadIdx.x] += sd[threadIdx.x + h];
    __syncthreads();
  }
  if (threadIdx.x == 0) {
    float beta  = fmaxf((float)(sd[0] / (double)NW), 1e-5f);
    float gamma = fmaxf(__uint_as_float(gbits[0]), 1e-5f);
    params[0] = 128.0f / gamma;          // activation scale (q/gamma)
    params[1] = beta;                    // weight divisor
    params[2] = beta * gamma / 128.0f;   // output rescale
  }
}

// ---------------- quantization (int8 outputs) ----------------

__global__ void quant_x_kernel(const float* __restrict__ x,
                               char* __restrict__ xq,
                               const float* __restrict__ params, int n16) {
  float s = params[0];
  int stride = gridDim.x * blockDim.x;
  for (int i = blockIdx.x * blockDim.x + threadIdx.x; i < n16; i += stride) {
    const f32x4* p = (const f32x4*)(x + (size_t)i * 16);
    s8x16 o;
#pragma unroll
    for (int v = 0; v < 4; ++v) {
      f32x4 t = p[v];
#pragma unroll
      for (int k = 0; k < 4; ++k) {
        float r = fminf(fmaxf(rintf(t[k] * s), -128.f), 127.f);
        o[v * 4 + k] = (char)(int)r;
      }
    }
    *(s8x16*)(xq + (size_t)i * 16) = o;
  }
}

__global__ void quant_w_kernel(const float* __restrict__ w,
                               char* __restrict__ wq,
                               const float* __restrict__ params, int n16) {
  float beta = params[1];
  int stride = gridDim.x * blockDim.x;
  for (int i = blockIdx.x * blockDim.x + threadIdx.x; i < n16; i += stride) {
    const f32x4* p = (const f32x4*)(w + (size_t)i * 16);
    s8x16 o;
#pragma unroll
    for (int v = 0; v < 4; ++v) {
      f32x4 t = p[v];
#pragma unroll
      for (int k = 0; k < 4; ++k) {
        // round_clip(|w|/beta, -1, 1): nonneg -> {0,1}; IEEE div matches ref rounding
        o[v * 4 + k] = (rintf(fabsf(t[k]) / beta) >= 1.0f) ? (char)1 : (char)0;
      }
    }
    *(s8x16*)(wq + (size_t)i * 16) = o;
  }
}

// ---------------- GEMM (m97-structure, int8: 128x128 tile, BK=64, mfma_i32_16x16x64_i8)
// C[m][n] = sum_k A[m][k] * B[n][k]  (B stored row-major [N][K] == B^T input)

__global__ __launch_bounds__(256) void gemm_kernel(
    const char* __restrict__ A,   // xq int8 [M][K]
    const char* __restrict__ B,   // wq int8 [N][K]
    float* __restrict__ C,        // [M][N] fp32
    const float* __restrict__ params) {
  __shared__ __align__(16) char As[128 * 64];
  __shared__ __align__(16) char Bs[128 * 64];

  const int tid  = threadIdx.x;
  const int lane = tid & 63, wid = tid >> 6;
  const int wr = wid >> 1, wc = wid & 1;          // 2x2 waves, each 64x64
  const int r16 = lane & 15, q4 = lane >> 4;
  const int m0 = blockIdx.y * 128, n0 = blockIdx.x * 128;
  const float sc = params[2];

  // staging: two 16B rounds per tile per operand (tile = 128 rows x 64 bytes)
  const int i0 = tid, i1 = 256 + tid;
  const char* ga0 = A + (size_t)(m0 + (i0 >> 2)) * K + (i0 & 3) * 16;
  const char* ga1 = A + (size_t)(m0 + (i1 >> 2)) * K + (i1 & 3) * 16;
  const char* gb0 = B + (size_t)(n0 + (i0 >> 2)) * K + (i0 & 3) * 16;
  const char* gb1 = B + (size_t)(n0 + (i1 >> 2)) * K + (i1 & 3) * 16;
  char* la0 = &As[i0 * 16];
  char* la1 = &As[i1 * 16];
  char* lb0 = &Bs[i0 * 16];
  char* lb1 = &Bs[i1 * 16];

  int aoff[4], boff[4];
#pragma unroll
  for (int i = 0; i < 4; ++i) {
    aoff[i] = (wr * 64 + i * 16 + r16) * 64 + q4 * 16;   // byte offsets
    boff[i] = (wc * 64 + i * 16 + r16) * 64 + q4 * 16;
  }

  i32x4 acc[4][4] = {};

  for (int kt = 0; kt < K / 64; ++kt) {
    const int ko = kt * 64;
    __builtin_amdgcn_global_load_lds((const GAS void*)(ga0 + ko), (LAS void*)la0, 16, 0, 0);
    __builtin_amdgcn_global_load_lds((const GAS void*)(ga1 + ko), (LAS void*)la1, 16, 0, 0);
    __builtin_amdgcn_global_load_lds((const GAS void*)(gb0 + ko), (LAS void*)lb0, 16, 0, 0);
    __builtin_amdgcn_global_load_lds((const GAS void*)(gb1 + ko), (LAS void*)lb1, 16, 0, 0);
    __syncthreads();   // compiler emits vmcnt(0) drain before barrier

    i32x4 af[4], bf[4];
#pragma unroll
    for (int i = 0; i < 4; ++i) af[i] = *(const i32x4*)&As[aoff[i]];
#pragma unroll
    for (int j = 0; j < 4; ++j) bf[j] = *(const i32x4*)&Bs[boff[j]];
#pragma unroll
    for (int i = 0; i < 4; ++i)
#pragma unroll
      for (int j = 0; j < 4; ++j)
        acc[i][j] = __builtin_amdgcn_mfma_i32_16x16x64_i8(af[i], bf[j], acc[i][j], 0, 0, 0);
    __syncthreads();
  }

  // C/D layout (m89-verified, dtype-independent): col = lane&15, row = (lane>>4)*4 + reg
  const int crow = m0 + wr * 64 + q4 * 4;
  const int ccol = n0 + wc * 64 + r16;
#pragma unroll
  for (int i = 0; i < 4; ++i)
#pragma unroll
    for (int j = 0; j < 4; ++j)
#pragma unroll
      for (int r = 0; r < 4; ++r)
        C[(size_t)(crow + i * 16 + r) * N + (ccol + j * 16)] = (float)acc[i][j][r] * sc;
}

// ---------------- launch ----------------

extern "C" void kernel_launch(void* const* d_in, const int* in_sizes, int n_in,
                              void* d_out, int out_size, void* d_ws, size_t ws_size,
                              hipStream_t stream) {
  const float* x = (const float*)d_in[0];
  const float* w = (const float*)d_in[1];
  float* out = (float*)d_out;
  char* ws = (char*)d_ws;

  unsigned* gamma_bits = (unsigned*)ws;            // 4 B
  float*    params     = (float*)(ws + 16);        // 3 floats
  float*    partials   = (float*)(ws + 256);       // 2048 floats
  char*     xq = ws + 16384;                       // 33,554,432 B
  char*     wq = ws + 16384 + (size_t)NX;          // 67,108,864 B

  hipMemsetAsync(ws, 0, 256, stream);  // zero gamma accumulator each call

  reduce_absmax_kernel<<<NPART, 256, 0, stream>>>(x, gamma_bits, (int)(NX / 4));
  reduce_abssum_kernel<<<NPART, 256, 0, stream>>>(w, partials, (int)(NW / 4));
  finalize_kernel<<<1, 256, 0, stream>>>(gamma_bits, partials, params);
  quant_x_kernel<<<2048, 256, 0, stream>>>(x, xq, params, (int)(NX / 16));
  quant_w_kernel<<<2048, 256, 0, stream>>>(w, wq, params, (int)(NW / 16));

  dim3 grid(N / 128, M / 128);
  gemm_kernel<<<grid, 256, 0, stream>>>(xq, wq, out, params);
}

// Round 4
// 842.482 us; speedup vs baseline: 1.7183x; 1.0248x over previous
//
#include <hip/hip_runtime.h>

typedef float f32x4 __attribute__((ext_vector_type(4)));
typedef int   i32x4 __attribute__((ext_vector_type(4)));
typedef char  s8x16 __attribute__((ext_vector_type(16)));

#define GAS __attribute__((address_space(1)))
#define LAS __attribute__((address_space(3)))

constexpr int M = 8192;       // B*S
constexpr int N = 16384;      // D_OUT
constexpr int K = 4096;       // D_IN
constexpr long long NX = (long long)M * K;   // 33,554,432
constexpr long long NW = (long long)N * K;   // 67,108,864
constexpr int NPART = 2048;
constexpr int BK = 64;                // K-bytes per tile (i8: 1 B/elem)
constexpr int NT = K / BK;            // 64 K-tiles
constexpr int OP_BYTES = 128 * BK;    // 8192 B per operand tile
constexpr int BUF_BYTES = 2 * OP_BYTES;

// ---------------- reductions ----------------

__global__ void reduce_absmax_kernel(const float* __restrict__ x,
                                     unsigned* __restrict__ gmax, int n4) {
  float m = 0.f;
  int stride = gridDim.x * blockDim.x;
  for (int i = blockIdx.x * blockDim.x + threadIdx.x; i < n4; i += stride) {
    f32x4 v = *(const f32x4*)(x + (size_t)i * 4);
    m = fmaxf(m, fmaxf(fmaxf(fabsf(v[0]), fabsf(v[1])),
                       fmaxf(fabsf(v[2]), fabsf(v[3]))));
  }
#pragma unroll
  for (int off = 32; off > 0; off >>= 1) m = fmaxf(m, __shfl_down(m, off));
  __shared__ float sm[4];
  int lane = threadIdx.x & 63, wid = threadIdx.x >> 6;
  if (lane == 0) sm[wid] = m;
  __syncthreads();
  if (threadIdx.x == 0) {
    m = fmaxf(fmaxf(sm[0], sm[1]), fmaxf(sm[2], sm[3]));
    atomicMax(gmax, __float_as_uint(m));  // |x| >= 0: bit-order == float-order
  }
}

__global__ void reduce_abssum_kernel(const float* __restrict__ w,
                                     float* __restrict__ partials, int n4) {
  float s = 0.f;
  int stride = gridDim.x * blockDim.x;
  for (int i = blockIdx.x * blockDim.x + threadIdx.x; i < n4; i += stride) {
    f32x4 v = *(const f32x4*)(w + (size_t)i * 4);
    s += fabsf(v[0]) + fabsf(v[1]) + fabsf(v[2]) + fabsf(v[3]);
  }
#pragma unroll
  for (int off = 32; off > 0; off >>= 1) s += __shfl_down(s, off);
  __shared__ float sm[4];
  int lane = threadIdx.x & 63, wid = threadIdx.x >> 6;
  if (lane == 0) sm[wid] = s;
  __syncthreads();
  if (threadIdx.x == 0) partials[blockIdx.x] = (sm[0] + sm[1]) + (sm[2] + sm[3]);
}

__global__ void finalize_kernel(const unsigned* __restrict__ gbits,
                                const float* __restrict__ partials,
                                float* __restrict__ params) {
  __shared__ double sd[256];
  double s = 0.0;
  for (int i = threadIdx.x; i < NPART; i += 256) s += (double)partials[i];
  sd[threadIdx.x] = s;
  __syncthreads();
  for (int h = 128; h > 0; h >>= 1) {
    if (threadIdx.x < h) sd[threadIdx.x] += sd[threadIdx.x + h];
    __syncthreads();
  }
  if (threadIdx.x == 0) {
    float beta  = fmaxf((float)(sd[0] / (double)NW), 1e-5f);
    float gamma = fmaxf(__uint_as_float(gbits[0]), 1e-5f);
    params[0] = 128.0f / gamma;          // activation scale (q/gamma)
    params[1] = beta;                    // weight divisor
    params[2] = beta * gamma / 128.0f;   // output rescale
  }
}

// ---------------- quantization (int8 outputs) ----------------

__global__ void quant_x_kernel(const float* __restrict__ x,
                               char* __restrict__ xq,
                               const float* __restrict__ params, int n16) {
  float s = params[0];
  int stride = gridDim.x * blockDim.x;
  for (int i = blockIdx.x * blockDim.x + threadIdx.x; i < n16; i += stride) {
    const f32x4* p = (const f32x4*)(x + (size_t)i * 16);
    s8x16 o;
#pragma unroll
    for (int v = 0; v < 4; ++v) {
      f32x4 t = p[v];
#pragma unroll
      for (int k = 0; k < 4; ++k) {
        float r = fminf(fmaxf(rintf(t[k] * s), -128.f), 127.f);
        o[v * 4 + k] = (char)(int)r;
      }
    }
    *(s8x16*)(xq + (size_t)i * 16) = o;
  }
}

__global__ void quant_w_kernel(const float* __restrict__ w,
                               char* __restrict__ wq,
                               const float* __restrict__ params, int n16) {
  float beta = params[1];
  int stride = gridDim.x * blockDim.x;
  for (int i = blockIdx.x * blockDim.x + threadIdx.x; i < n16; i += stride) {
    const f32x4* p = (const f32x4*)(w + (size_t)i * 16);
    s8x16 o;
#pragma unroll
    for (int v = 0; v < 4; ++v) {
      f32x4 t = p[v];
#pragma unroll
      for (int k = 0; k < 4; ++k) {
        // round_clip(|w|/beta, -1, 1): nonneg -> {0,1}; IEEE div matches ref rounding
        o[v * 4 + k] = (rintf(fabsf(t[k]) / beta) >= 1.0f) ? (char)1 : (char)0;
      }
    }
    *(s8x16*)(wq + (size_t)i * 16) = o;
  }
}

// ---------------- GEMM: 128x128 i8 tile, BK=64, 3-deep counted-vmcnt pipeline
// C[m][n] = sum_k A[m][k] * B[n][k]  (B row-major [N][K] == B^T input)
// T4: raw s_barrier + vmcnt(4) — next tile's 4 loads stay in flight.
// T2: 2-BIT slot swizzle swz(row) = ((row>>1)&3)<<4 (bits 4-5 only — stays
//     inside the 64B row).  Linear LDS dest (global_load_lds requirement) +
//     swizzled global source col + matching swizzled ds_read col (rule #21).
// T5: setprio(1) around the 16-MFMA cluster.

__global__ __launch_bounds__(256) void gemm_kernel(
    const char* __restrict__ A,   // xq int8 [M][K]
    const char* __restrict__ B,   // wq int8 [N][K]
    float* __restrict__ C,        // [M][N] fp32
    const float* __restrict__ params) {
  __shared__ __align__(16) char lds[3 * BUF_BYTES];   // 48 KiB

  const int tid  = threadIdx.x;
  const int lane = tid & 63, wid = tid >> 6;
  const int wr = wid >> 1, wc = wid & 1;          // 2x2 waves, each 64x64
  const int r16 = lane & 15, q4 = lane >> 4;
  const int m0 = blockIdx.y * 128, n0 = blockIdx.x * 128;

  // Staging: thread i writes LDS bytes [i*16, i*16+16) linearly (row = i>>2,
  // slot = i&3).  Global source col is slot^swz(row) so LDS holds the
  // swizzled layout: LDS[row][s*16+b] = global[row][(s ^ swz)*16 + b].
  const int i0 = tid, i1 = 256 + tid;
  const int row0 = i0 >> 2, row1 = i1 >> 2;
  const int c0 = ((i0 & 3) * 16) ^ (((row0 >> 1) & 3) << 4);
  const int c1 = ((i1 & 3) * 16) ^ (((row1 >> 1) & 3) << 4);
  const char* ga0 = A + (size_t)(m0 + row0) * K + c0;
  const char* ga1 = A + (size_t)(m0 + row1) * K + c1;
  const char* gb0 = B + (size_t)(n0 + row0) * K + c0;
  const char* gb1 = B + (size_t)(n0 + row1) * K + c1;

  // Fragment reads: want global[row][q4*16 .. +16) -> LDS col (q4 ^ swz)*16.
  // row = (mult of 16) + r16, so swz(row) = ((r16>>1)&3)<<4.
  int aoff[4], boff[4];
#pragma unroll
  for (int i = 0; i < 4; ++i) {
    const int sw = (q4 * 16) ^ (((r16 >> 1) & 3) << 4);
    aoff[i] = (wr * 64 + i * 16 + r16) * BK + sw;
    boff[i] = (wc * 64 + i * 16 + r16) * BK + sw;
  }

  i32x4 acc[4][4] = {};

  auto stage = [&](int t, int buf) {
    char* la = lds + buf * BUF_BYTES;
    char* lb = la + OP_BYTES;
    const int ko = t * BK;
    __builtin_amdgcn_global_load_lds((const GAS void*)(ga0 + ko), (LAS void*)(la + i0 * 16), 16, 0, 0);
    __builtin_amdgcn_global_load_lds((const GAS void*)(ga1 + ko), (LAS void*)(la + i1 * 16), 16, 0, 0);
    __builtin_amdgcn_global_load_lds((const GAS void*)(gb0 + ko), (LAS void*)(lb + i0 * 16), 16, 0, 0);
    __builtin_amdgcn_global_load_lds((const GAS void*)(gb1 + ko), (LAS void*)(lb + i1 * 16), 16, 0, 0);
  };

  auto compute = [&](int buf) {
    const char* la = lds + buf * BUF_BYTES;
    const char* lb = la + OP_BYTES;
    i32x4 af[4], bf[4];
#pragma unroll
    for (int i = 0; i < 4; ++i) af[i] = *(const i32x4*)(la + aoff[i]);
#pragma unroll
    for (int j = 0; j < 4; ++j) bf[j] = *(const i32x4*)(lb + boff[j]);
    __builtin_amdgcn_s_setprio(1);
#pragma unroll
    for (int i = 0; i < 4; ++i)
#pragma unroll
      for (int j = 0; j < 4; ++j)
        acc[i][j] = __builtin_amdgcn_mfma_i32_16x16x64_i8(af[i], bf[j], acc[i][j], 0, 0, 0);
    __builtin_amdgcn_s_setprio(0);
  };

  // prologue: tiles 0,1 in flight (8 vm ops)
  stage(0, 0);
  stage(1, 1);

  int cb = 0;   // buffer of tile kt
  int sb = 2;   // buffer of tile kt+2
  for (int kt = 0; kt < NT - 2; ++kt) {
    // outstanding: tiles kt, kt+1 (8 ops); in-order retirement -> vmcnt(4)
    // guarantees tile kt fully in LDS (this wave's share).
    asm volatile("s_waitcnt vmcnt(4)" ::: "memory");
    __builtin_amdgcn_sched_barrier(0);
    // barrier: (a) all waves' tile-kt shares resident; (b) all waves are done
    // reading tile kt-1 (its ds_reads retired before their prior-iter MFMAs),
    // so overwriting its buffer (sb) below is race-free.
    __builtin_amdgcn_s_barrier();
    __builtin_amdgcn_sched_barrier(0);
    stage(kt + 2, sb);          // issue early; stays in flight across barriers
    compute(cb);
    cb = (cb == 2) ? 0 : cb + 1;
    sb = (sb == 2) ? 0 : sb + 1;
  }
  // kt = NT-2: outstanding tiles NT-2, NT-1 -> vmcnt(4); no stage
  asm volatile("s_waitcnt vmcnt(4)" ::: "memory");
  __builtin_amdgcn_sched_barrier(0);
  __builtin_amdgcn_s_barrier();
  __builtin_amdgcn_sched_barrier(0);
  compute(cb);
  cb = (cb == 2) ? 0 : cb + 1;
  // kt = NT-1: drain
  asm volatile("s_waitcnt vmcnt(0)" ::: "memory");
  __builtin_amdgcn_sched_barrier(0);
  __builtin_amdgcn_s_barrier();
  __builtin_amdgcn_sched_barrier(0);
  compute(cb);

  // epilogue: C/D layout (m89-verified, dtype-independent):
  // col = lane&15, row = (lane>>4)*4 + reg
  const float sc = params[2];
  const int crow = m0 + wr * 64 + q4 * 4;
  const int ccol = n0 + wc * 64 + r16;
#pragma unroll
  for (int i = 0; i < 4; ++i)
#pragma unroll
    for (int j = 0; j < 4; ++j)
#pragma unroll
      for (int r = 0; r < 4; ++r)
        C[(size_t)(crow + i * 16 + r) * N + (ccol + j * 16)] = (float)acc[i][j][r] * sc;
}

// ---------------- launch ----------------

extern "C" void kernel_launch(void* const* d_in, const int* in_sizes, int n_in,
                              void* d_out, int out_size, void* d_ws, size_t ws_size,
                              hipStream_t stream) {
  const float* x = (const float*)d_in[0];
  const float* w = (const float*)d_in[1];
  float* out = (float*)d_out;
  char* ws = (char*)d_ws;

  unsigned* gamma_bits = (unsigned*)ws;            // 4 B
  float*    params     = (float*)(ws + 16);        // 3 floats
  float*    partials   = (float*)(ws + 256);       // 2048 floats
  char*     xq = ws + 16384;                       // 33,554,432 B
  char*     wq = ws + 16384 + (size_t)NX;          // 67,108,864 B

  hipMemsetAsync(ws, 0, 256, stream);  // zero gamma accumulator each call

  reduce_absmax_kernel<<<NPART, 256, 0, stream>>>(x, gamma_bits, (int)(NX / 4));
  reduce_abssum_kernel<<<NPART, 256, 0, stream>>>(w, partials, (int)(NW / 4));
  finalize_kernel<<<1, 256, 0, stream>>>(gamma_bits, partials, params);
  quant_x_kernel<<<2048, 256, 0, stream>>>(x, xq, params, (int)(NX / 16));
  quant_w_kernel<<<2048, 256, 0, stream>>>(w, wq, params, (int)(NW / 16));

  dim3 grid(N / 128, M / 128);
  gemm_kernel<<<grid, 256, 0, stream>>>(xq, wq, out, params);
}

// Round 5
// 765.194 us; speedup vs baseline: 1.8918x; 1.1010x over previous
//
#include <hip/hip_runtime.h>

typedef float f32x4 __attribute__((ext_vector_type(4)));
typedef int   i32x4 __attribute__((ext_vector_type(4)));
typedef char  s8x16 __attribute__((ext_vector_type(16)));

#define GAS __attribute__((address_space(1)))
#define LAS __attribute__((address_space(3)))

constexpr int M = 8192;       // B*S
constexpr int N = 16384;      // D_OUT
constexpr int K = 4096;       // D_IN
constexpr long long NX = (long long)M * K;   // 33,554,432
constexpr long long NW = (long long)N * K;   // 67,108,864
constexpr int NPART = 2048;

// ---------------- reductions ----------------

__global__ void reduce_absmax_kernel(const float* __restrict__ x,
                                     unsigned* __restrict__ gmax, int n4) {
  float m = 0.f;
  int stride = gridDim.x * blockDim.x;
  for (int i = blockIdx.x * blockDim.x + threadIdx.x; i < n4; i += stride) {
    f32x4 v = *(const f32x4*)(x + (size_t)i * 4);
    m = fmaxf(m, fmaxf(fmaxf(fabsf(v[0]), fabsf(v[1])),
                       fmaxf(fabsf(v[2]), fabsf(v[3]))));
  }
#pragma unroll
  for (int off = 32; off > 0; off >>= 1) m = fmaxf(m, __shfl_down(m, off));
  __shared__ float sm[4];
  int lane = threadIdx.x & 63, wid = threadIdx.x >> 6;
  if (lane == 0) sm[wid] = m;
  __syncthreads();
  if (threadIdx.x == 0) {
    m = fmaxf(fmaxf(sm[0], sm[1]), fmaxf(sm[2], sm[3]));
    atomicMax(gmax, __float_as_uint(m));  // |x| >= 0: bit-order == float-order
  }
}

__global__ void reduce_abssum_kernel(const float* __restrict__ w,
                                     float* __restrict__ partials, int n4) {
  float s = 0.f;
  int stride = gridDim.x * blockDim.x;
  for (int i = blockIdx.x * blockDim.x + threadIdx.x; i < n4; i += stride) {
    f32x4 v = *(const f32x4*)(w + (size_t)i * 4);
    s += fabsf(v[0]) + fabsf(v[1]) + fabsf(v[2]) + fabsf(v[3]);
  }
#pragma unroll
  for (int off = 32; off > 0; off >>= 1) s += __shfl_down(s, off);
  __shared__ float sm[4];
  int lane = threadIdx.x & 63, wid = threadIdx.x >> 6;
  if (lane == 0) sm[wid] = s;
  __syncthreads();
  if (threadIdx.x == 0) partials[blockIdx.x] = (sm[0] + sm[1]) + (sm[2] + sm[3]);
}

__global__ void finalize_kernel(const unsigned* __restrict__ gbits,
                                const float* __restrict__ partials,
                                float* __restrict__ params) {
  __shared__ double sd[256];
  double s = 0.0;
  for (int i = threadIdx.x; i < NPART; i += 256) s += (double)partials[i];
  sd[threadIdx.x] = s;
  __syncthreads();
  for (int h = 128; h > 0; h >>= 1) {
    if (threadIdx.x < h) sd[threadIdx.x] += sd[threadIdx.x + h];
    __syncthreads();
  }
  if (threadIdx.x == 0) {
    float beta  = fmaxf((float)(sd[0] / (double)NW), 1e-5f);
    float gamma = fmaxf(__uint_as_float(gbits[0]), 1e-5f);
    params[0] = 128.0f / gamma;          // activation scale (q/gamma)
    params[1] = beta;                    // weight divisor
    params[2] = beta * gamma / 128.0f;   // output rescale
  }
}

// ---------------- quantization (int8 outputs) ----------------

__global__ void quant_x_kernel(const float* __restrict__ x,
                               char* __restrict__ xq,
                               const float* __restrict__ params, int n16) {
  float s = params[0];
  int stride = gridDim.x * blockDim.x;
  for (int i = blockIdx.x * blockDim.x + threadIdx.x; i < n16; i += stride) {
    const f32x4* p = (const f32x4*)(x + (size_t)i * 16);
    s8x16 o;
#pragma unroll
    for (int v = 0; v < 4; ++v) {
      f32x4 t = p[v];
#pragma unroll
      for (int k = 0; k < 4; ++k) {
        float r = fminf(fmaxf(rintf(t[k] * s), -128.f), 127.f);
        o[v * 4 + k] = (char)(int)r;
      }
    }
    *(s8x16*)(xq + (size_t)i * 16) = o;
  }
}

__global__ void quant_w_kernel(const float* __restrict__ w,
                               char* __restrict__ wq,
                               const float* __restrict__ params, int n16) {
  float beta = params[1];
  int stride = gridDim.x * blockDim.x;
  for (int i = blockIdx.x * blockDim.x + threadIdx.x; i < n16; i += stride) {
    const f32x4* p = (const f32x4*)(w + (size_t)i * 16);
    s8x16 o;
#pragma unroll
    for (int v = 0; v < 4; ++v) {
      f32x4 t = p[v];
#pragma unroll
      for (int k = 0; k < 4; ++k) {
        // round_clip(|w|/beta, -1, 1): nonneg -> {0,1}; IEEE div matches ref rounding
        o[v * 4 + k] = (rintf(fabsf(t[k]) / beta) >= 1.0f) ? (char)1 : (char)0;
      }
    }
    *(s8x16*)(wq + (size_t)i * 16) = o;
  }
}

// ---------------- GEMM: 256x256 i8 tile, BK=128B, 8 waves, 4-phase schedule
// C[m][n] = sum_k A[m][k] * B[n][k]  (B row-major [N][K] == B^T input)
// LDS 128 KiB = 2 buf x (A 32K + B 32K).  Per K-tile: 4 phases, 16 MFMA each,
// phase = (k-half, n-half).  Batch of 8 global_load_lds issued at phase 0
// after the barrier (1 tile ahead); vmcnt(0) there waits only on loads issued
// a full tile (~4 phases) earlier.  3-bit slot swizzle slot^=(row&7) gives
// conflict-free ds_read_b128; staging source pre-swizzled per-lane, linear
// LDS dest (rule #21).  T1 bijective XCD swizzle; T5 setprio per cluster.

__global__ __launch_bounds__(512, 2) void gemm_kernel(
    const char* __restrict__ A,   // xq int8 [M][K]
    const char* __restrict__ B,   // wq int8 [N][K]
    float* __restrict__ C,        // [M][N] fp32
    const float* __restrict__ params) {
  __shared__ __align__(16) char lds[131072];

  const int tid  = threadIdx.x;
  const int lane = tid & 63, wid = tid >> 6;
  const int wm = wid >> 2, wn = wid & 3;          // 2x4 waves, each 128x64
  const int r16 = lane & 15, q4 = lane >> 4;

  // T1: bijective XCD swizzle (2048 blocks % 8 == 0), mt-major chunks:
  // each XCD owns 4 consecutive A-panels x all 64 N-tiles.
  const int wg = (blockIdx.x & 7) * 256 + (blockIdx.x >> 3);
  const int m0 = (wg >> 6) * 256, n0 = (wg & 63) * 256;

  // ---- staging geometry ----
  // Per buffer: A[256][128] at +0, B[256][128] at +32768.  One gload_lds
  // instruction covers 8 rows x 128B: wave w, instr j -> rows (w*16+j*8..+8),
  // lane l -> row +(l>>3), LDS slot l&7 (linear dest), global slot
  // (l&7)^(l>>3)  => LDS[row][s] = global[row][s ^ (row&7)].
  const int l8 = lane >> 3;
  const int cswz = ((lane & 7) ^ l8) * 16;
  const char* Ar = A + (size_t)(m0 + wid * 16 + l8) * K + cswz;
  const char* Br = B + (size_t)(n0 + wid * 16 + l8) * K + cswz;
  const int dbase = wid * 2048 + lane * 16;

  auto stage = [&](int t, int b) {
    char* L = lds + b * 65536;
    const char* a0 = Ar + t * 128;
    const char* b0 = Br + t * 128;
    __builtin_amdgcn_global_load_lds((const GAS void*)(a0),               (LAS void*)(L + dbase),                16, 0, 0);
    __builtin_amdgcn_global_load_lds((const GAS void*)(a0 + 8 * K),       (LAS void*)(L + dbase + 1024),         16, 0, 0);
    __builtin_amdgcn_global_load_lds((const GAS void*)(a0 + 128 * K),     (LAS void*)(L + dbase + 16384),        16, 0, 0);
    __builtin_amdgcn_global_load_lds((const GAS void*)(a0 + 136 * K),     (LAS void*)(L + dbase + 17408),        16, 0, 0);
    __builtin_amdgcn_global_load_lds((const GAS void*)(b0),               (LAS void*)(L + dbase + 32768),        16, 0, 0);
    __builtin_amdgcn_global_load_lds((const GAS void*)(b0 + 8 * K),       (LAS void*)(L + dbase + 33792),        16, 0, 0);
    __builtin_amdgcn_global_load_lds((const GAS void*)(b0 + 128 * K),     (LAS void*)(L + dbase + 49152),        16, 0, 0);
    __builtin_amdgcn_global_load_lds((const GAS void*)(b0 + 136 * K),     (LAS void*)(L + dbase + 50176),        16, 0, 0);
  };

  // ---- fragment read offsets (swizzled): want global slot kh*4+q4 of row
  // -> LDS slot (kh*4+q4)^(row&7), row&7 == r16&7 (bases are multiples of 16/64).
  int aoff[8][2], boff[4][2];
#pragma unroll
  for (int i = 0; i < 8; ++i)
#pragma unroll
    for (int kh = 0; kh < 2; ++kh)
      aoff[i][kh] = (wm * 128 + i * 16 + r16) * 128 + (((kh * 4 + q4) ^ (r16 & 7)) * 16);
#pragma unroll
  for (int j = 0; j < 4; ++j)
#pragma unroll
    for (int kh = 0; kh < 2; ++kh)
      boff[j][kh] = 32768 + (wn * 64 + j * 16 + r16) * 128 + (((kh * 4 + q4) ^ (r16 & 7)) * 16);

  i32x4 acc[8][4] = {};
  i32x4 afr[8], bfr0, bfr1;

  stage(0, 0);   // prologue: tile 0 in flight

  for (int t = 0; t < 32; ++t) {
    const char* buf = lds + (t & 1) * 65536;
    // ---- phase 0: (kh=0, n-half=0) ----
    asm volatile("s_waitcnt vmcnt(0)" ::: "memory");   // tile t resident (issued ~4 phases ago)
    __builtin_amdgcn_sched_barrier(0);
    __builtin_amdgcn_s_barrier();   // all waves: tile t ready AND tile t-1 reads retired
    __builtin_amdgcn_sched_barrier(0);
    if (t + 1 < 32) stage(t + 1, (t + 1) & 1);   // overwrites buf[(t-1)&1]: safe
#pragma unroll
    for (int i = 0; i < 8; ++i) afr[i] = *(const i32x4*)(buf + aoff[i][0]);
    bfr0 = *(const i32x4*)(buf + boff[0][0]);
    bfr1 = *(const i32x4*)(buf + boff[1][0]);
    __builtin_amdgcn_s_setprio(1);
#pragma unroll
    for (int i = 0; i < 8; ++i) {
      acc[i][0] = __builtin_amdgcn_mfma_i32_16x16x64_i8(afr[i], bfr0, acc[i][0], 0, 0, 0);
      acc[i][1] = __builtin_amdgcn_mfma_i32_16x16x64_i8(afr[i], bfr1, acc[i][1], 0, 0, 0);
    }
    __builtin_amdgcn_s_setprio(0);
    __builtin_amdgcn_s_barrier();
    // ---- phase 1: (kh=0, n-half=1) — A frags reused ----
    bfr0 = *(const i32x4*)(buf + boff[2][0]);
    bfr1 = *(const i32x4*)(buf + boff[3][0]);
    __builtin_amdgcn_s_setprio(1);
#pragma unroll
    for (int i = 0; i < 8; ++i) {
      acc[i][2] = __builtin_amdgcn_mfma_i32_16x16x64_i8(afr[i], bfr0, acc[i][2], 0, 0, 0);
      acc[i][3] = __builtin_amdgcn_mfma_i32_16x16x64_i8(afr[i], bfr1, acc[i][3], 0, 0, 0);
    }
    __builtin_amdgcn_s_setprio(0);
    __builtin_amdgcn_s_barrier();
    // ---- phase 2: (kh=1, n-half=0) ----
#pragma unroll
    for (int i = 0; i < 8; ++i) afr[i] = *(const i32x4*)(buf + aoff[i][1]);
    bfr0 = *(const i32x4*)(buf + boff[0][1]);
    bfr1 = *(const i32x4*)(buf + boff[1][1]);
    __builtin_amdgcn_s_setprio(1);
#pragma unroll
    for (int i = 0; i < 8; ++i) {
      acc[i][0] = __builtin_amdgcn_mfma_i32_16x16x64_i8(afr[i], bfr0, acc[i][0], 0, 0, 0);
      acc[i][1] = __builtin_amdgcn_mfma_i32_16x16x64_i8(afr[i], bfr1, acc[i][1], 0, 0, 0);
    }
    __builtin_amdgcn_s_setprio(0);
    __builtin_amdgcn_s_barrier();
    // ---- phase 3: (kh=1, n-half=1) ----
    bfr0 = *(const i32x4*)(buf + boff[2][1]);
    bfr1 = *(const i32x4*)(buf + boff[3][1]);
    __builtin_amdgcn_s_setprio(1);
#pragma unroll
    for (int i = 0; i < 8; ++i) {
      acc[i][2] = __builtin_amdgcn_mfma_i32_16x16x64_i8(afr[i], bfr0, acc[i][2], 0, 0, 0);
      acc[i][3] = __builtin_amdgcn_mfma_i32_16x16x64_i8(afr[i], bfr1, acc[i][3], 0, 0, 0);
    }
    __builtin_amdgcn_s_setprio(0);
    // no trailing barrier: next iteration's phase 0 provides it
  }

  // epilogue: C/D layout (m89-verified, dtype-independent):
  // col = lane&15, row = (lane>>4)*4 + reg
  const float sc = params[2];
  const int crow = m0 + wm * 128 + q4 * 4;
  const int ccol = n0 + wn * 64 + r16;
#pragma unroll
  for (int i = 0; i < 8; ++i)
#pragma unroll
    for (int jj = 0; jj < 4; ++jj)
#pragma unroll
      for (int r = 0; r < 4; ++r)
        C[(size_t)(crow + i * 16 + r) * N + (ccol + jj * 16)] = (float)acc[i][jj][r] * sc;
}

// ---------------- launch ----------------

extern "C" void kernel_launch(void* const* d_in, const int* in_sizes, int n_in,
                              void* d_out, int out_size, void* d_ws, size_t ws_size,
                              hipStream_t stream) {
  const float* x = (const float*)d_in[0];
  const float* w = (const float*)d_in[1];
  float* out = (float*)d_out;
  char* ws = (char*)d_ws;

  unsigned* gamma_bits = (unsigned*)ws;            // 4 B
  float*    params     = (float*)(ws + 16);        // 3 floats
  float*    partials   = (float*)(ws + 256);       // 2048 floats
  char*     xq = ws + 16384;                       // 33,554,432 B
  char*     wq = ws + 16384 + (size_t)NX;          // 67,108,864 B

  hipMemsetAsync(ws, 0, 256, stream);  // zero gamma accumulator each call

  reduce_absmax_kernel<<<NPART, 256, 0, stream>>>(x, gamma_bits, (int)(NX / 4));
  reduce_abssum_kernel<<<NPART, 256, 0, stream>>>(w, partials, (int)(NW / 4));
  finalize_kernel<<<1, 256, 0, stream>>>(gamma_bits, partials, params);
  quant_x_kernel<<<2048, 256, 0, stream>>>(x, xq, params, (int)(NX / 16));
  quant_w_kernel<<<2048, 256, 0, stream>>>(w, wq, params, (int)(NW / 16));

  gemm_kernel<<<2048, 512, 0, stream>>>(xq, wq, out, params);
}

// Round 6
// 756.334 us; speedup vs baseline: 1.9140x; 1.0117x over previous
//
#include <hip/hip_runtime.h>

typedef float f32x4 __attribute__((ext_vector_type(4)));
typedef int   i32x4 __attribute__((ext_vector_type(4)));
typedef char  s8x16 __attribute__((ext_vector_type(16)));

#define GAS __attribute__((address_space(1)))
#define LAS __attribute__((address_space(3)))

constexpr int M = 8192;       // B*S
constexpr int N = 16384;      // D_OUT
constexpr int K = 4096;       // D_IN
constexpr long long NX = (long long)M * K;   // 33,554,432
constexpr long long NW = (long long)N * K;   // 67,108,864
constexpr int NPART = 2048;

constexpr int BKB    = 64;               // K-bytes per tile (i8)
constexpr int NTT    = K / BKB;          // 64 K-tiles
constexpr int ABYTES = 256 * BKB;        // 16384
constexpr int BBYTES = 128 * BKB;        // 8192
constexpr int BUFB   = ABYTES + BBYTES;  // 24576

// ---------------- reductions ----------------

__global__ void reduce_absmax_kernel(const float* __restrict__ x,
                                     unsigned* __restrict__ gmax, int n4) {
  float m = 0.f;
  int stride = gridDim.x * blockDim.x;
  for (int i = blockIdx.x * blockDim.x + threadIdx.x; i < n4; i += stride) {
    f32x4 v = *(const f32x4*)(x + (size_t)i * 4);
    m = fmaxf(m, fmaxf(fmaxf(fabsf(v[0]), fabsf(v[1])),
                       fmaxf(fabsf(v[2]), fabsf(v[3]))));
  }
#pragma unroll
  for (int off = 32; off > 0; off >>= 1) m = fmaxf(m, __shfl_down(m, off));
  __shared__ float sm[4];
  int lane = threadIdx.x & 63, wid = threadIdx.x >> 6;
  if (lane == 0) sm[wid] = m;
  __syncthreads();
  if (threadIdx.x == 0) {
    m = fmaxf(fmaxf(sm[0], sm[1]), fmaxf(sm[2], sm[3]));
    atomicMax(gmax, __float_as_uint(m));  // |x| >= 0: bit-order == float-order
  }
}

__global__ void reduce_abssum_kernel(const float* __restrict__ w,
                                     float* __restrict__ partials, int n4) {
  float s = 0.f;
  int stride = gridDim.x * blockDim.x;
  for (int i = blockIdx.x * blockDim.x + threadIdx.x; i < n4; i += stride) {
    f32x4 v = *(const f32x4*)(w + (size_t)i * 4);
    s += fabsf(v[0]) + fabsf(v[1]) + fabsf(v[2]) + fabsf(v[3]);
  }
#pragma unroll
  for (int off = 32; off > 0; off >>= 1) s += __shfl_down(s, off);
  __shared__ float sm[4];
  int lane = threadIdx.x & 63, wid = threadIdx.x >> 6;
  if (lane == 0) sm[wid] = s;
  __syncthreads();
  if (threadIdx.x == 0) partials[blockIdx.x] = (sm[0] + sm[1]) + (sm[2] + sm[3]);
}

__global__ void finalize_kernel(const unsigned* __restrict__ gbits,
                                const float* __restrict__ partials,
                                float* __restrict__ params) {
  __shared__ double sd[256];
  double s = 0.0;
  for (int i = threadIdx.x; i < NPART; i += 256) s += (double)partials[i];
  sd[threadIdx.x] = s;
  __syncthreads();
  for (int h = 128; h > 0; h >>= 1) {
    if (threadIdx.x < h) sd[threadIdx.x] += sd[threadIdx.x + h];
    __syncthreads();
  }
  if (threadIdx.x == 0) {
    float beta  = fmaxf((float)(sd[0] / (double)NW), 1e-5f);
    float gamma = fmaxf(__uint_as_float(gbits[0]), 1e-5f);
    params[0] = 128.0f / gamma;          // activation scale (q/gamma)
    params[1] = beta;                    // weight divisor
    params[2] = beta * gamma / 128.0f;   // output rescale
  }
}

// ---------------- quantization (int8 outputs) ----------------

__global__ void quant_x_kernel(const float* __restrict__ x,
                               char* __restrict__ xq,
                               const float* __restrict__ params, int n16) {
  float s = params[0];
  int stride = gridDim.x * blockDim.x;
  for (int i = blockIdx.x * blockDim.x + threadIdx.x; i < n16; i += stride) {
    const f32x4* p = (const f32x4*)(x + (size_t)i * 16);
    s8x16 o;
#pragma unroll
    for (int v = 0; v < 4; ++v) {
      f32x4 t = p[v];
#pragma unroll
      for (int k = 0; k < 4; ++k) {
        float r = fminf(fmaxf(rintf(t[k] * s), -128.f), 127.f);
        o[v * 4 + k] = (char)(int)r;
      }
    }
    *(s8x16*)(xq + (size_t)i * 16) = o;
  }
}

__global__ void quant_w_kernel(const float* __restrict__ w,
                               char* __restrict__ wq,
                               const float* __restrict__ params, int n16) {
  float beta = params[1];
  int stride = gridDim.x * blockDim.x;
  for (int i = blockIdx.x * blockDim.x + threadIdx.x; i < n16; i += stride) {
    const f32x4* p = (const f32x4*)(w + (size_t)i * 16);
    s8x16 o;
#pragma unroll
    for (int v = 0; v < 4; ++v) {
      f32x4 t = p[v];
#pragma unroll
      for (int k = 0; k < 4; ++k) {
        // round_clip(|w|/beta, -1, 1): nonneg -> {0,1}; IEEE div matches ref rounding
        o[v * 4 + k] = (rintf(fabsf(t[k]) / beta) >= 1.0f) ? (char)1 : (char)0;
      }
    }
    *(s8x16*)(wq + (size_t)i * 16) = o;
  }
}

// ---------------- GEMM: 256x128 tile, 8 waves x 64x64, BK=64B, 3-buf ring
// C[m][n] = sum_k A[m][k] * B[n][k]  (B row-major [N][K] == B^T input)
// Geometry chosen for 2 blocks/CU (72 KiB LDS, <=128 VGPR/wave): two
// independent barrier domains per CU so one block's vmcnt/barrier/ds_read
// dead time hides under the other's MFMAs (m114 overlap).
// T4: counted vmcnt(3) — tile t+1's 3 loads stay in flight across barriers.
// T2: slot swizzle slot^=(row>>1)&3 (64B rows, 4 slots); linear LDS dest +
//     swizzled global source + matching swizzled ds_read (rule #21).
//     b128 read granules mod 8 = {0,4,1,5,2,6,3,7} -> conflict-free.
// T1: bijective XCD swizzle (4096 % 8 == 0).
// T5: setprio around MFMA cluster.

__global__ __launch_bounds__(512, 4) void gemm_kernel(
    const char* __restrict__ A,   // xq int8 [M][K]
    const char* __restrict__ B,   // wq int8 [N][K]
    float* __restrict__ C,        // [M][N] fp32
    const float* __restrict__ params) {
  __shared__ __align__(16) char lds[3 * BUFB];   // 72 KiB

  const int tid  = threadIdx.x;
  const int lane = tid & 63, wid = tid >> 6;
  const int wm = wid >> 1, wn = wid & 1;          // 4x2 waves, each 64x64
  const int r16 = lane & 15, q4 = lane >> 4;      // q4 in 0..3 == k-slot

  // T1: XCD swizzle; grid 4096 = 32 m-tiles x 128 n-tiles, m-major chunks.
  const int wg = (blockIdx.x & 7) * 512 + (blockIdx.x >> 3);
  const int m0 = (wg >> 7) * 256, n0 = (wg & 127) * 128;

  // ---- staging geometry ----
  // One gload_lds: 64 lanes x 16B = 16 rows x 64B.  lane l -> row +(l>>2),
  // LDS slot l&3 (linear dest), global slot (l&3)^((row>>1)&3).
  // row>>1&3 == (l>>3)&3 since per-instr row bases are multiples of 16.
  const int csw = (((lane & 3) ^ ((lane >> 3) & 3))) * 16;
  const char* gA = A + (size_t)(m0 + wid * 32 + (lane >> 2)) * K + csw;  // +j*16 rows
  const char* gB = B + (size_t)(n0 + wid * 16 + (lane >> 2)) * K + csw;
  const int dA = wid * 2048 + lane * 16;           // LDS A dest (+j*1024)
  const int dB = ABYTES + wid * 1024 + lane * 16;  // LDS B dest

  auto stage = [&](int t, int bo) {
    char* L = lds + bo;
    const char* a = gA + t * BKB;
    __builtin_amdgcn_global_load_lds((const GAS void*)a,              (LAS void*)(L + dA),        16, 0, 0);
    __builtin_amdgcn_global_load_lds((const GAS void*)(a + 16 * K),   (LAS void*)(L + dA + 1024), 16, 0, 0);
    __builtin_amdgcn_global_load_lds((const GAS void*)(gB + t * BKB), (LAS void*)(L + dB),        16, 0, 0);
  };

  // ---- fragment read offsets: global slot q4 of row -> LDS slot q4^((row>>1)&3),
  // row = base16 + r16 so swz = (r16>>1)&3.
  int aoff[4], boff[4];
  const int rsw = ((q4 ^ ((r16 >> 1) & 3)) * 16);
#pragma unroll
  for (int i = 0; i < 4; ++i)
    aoff[i] = (wm * 64 + i * 16 + r16) * BKB + rsw;
#pragma unroll
  for (int j = 0; j < 4; ++j)
    boff[j] = ABYTES + (wn * 64 + j * 16 + r16) * BKB + rsw;

  i32x4 acc[4][4] = {};

  auto compute = [&](int bo) {
    const char* buf = lds + bo;
    i32x4 af[4], bf[4];
#pragma unroll
    for (int i = 0; i < 4; ++i) af[i] = *(const i32x4*)(buf + aoff[i]);
#pragma unroll
    for (int j = 0; j < 4; ++j) bf[j] = *(const i32x4*)(buf + boff[j]);
    __builtin_amdgcn_s_setprio(1);
#pragma unroll
    for (int i = 0; i < 4; ++i)
#pragma unroll
      for (int j = 0; j < 4; ++j)
        acc[i][j] = __builtin_amdgcn_mfma_i32_16x16x64_i8(af[i], bf[j], acc[i][j], 0, 0, 0);
    __builtin_amdgcn_s_setprio(0);
  };

  // prologue: tiles 0,1 in flight (6 vm ops)
  stage(0, 0);
  stage(1, BUFB);

  int cb = 0, sb = 2 * BUFB;
  for (int t = 0; t < NTT - 1; ++t) {
    // outstanding: tiles t, t+1 (6 ops); in-order retirement -> vmcnt(3)
    // guarantees tile t resident (this wave's share).
    asm volatile("s_waitcnt vmcnt(3)" ::: "memory");
    __builtin_amdgcn_sched_barrier(0);
    // barrier: all waves' tile-t shares resident AND all waves done reading
    // tile t-1 (ds_reads retired before their MFMAs which precede arrival),
    // so stage(t+2) overwriting buf[t-1] below is race-free.
    __builtin_amdgcn_s_barrier();
    __builtin_amdgcn_sched_barrier(0);
    if (t + 2 < NTT) stage(t + 2, sb);
    compute(cb);
    cb = (cb == 2 * BUFB) ? 0 : cb + BUFB;
    sb = (sb == 2 * BUFB) ? 0 : sb + BUFB;
  }
  // final tile: only tile NTT-1's 3 loads outstanding -> full drain
  asm volatile("s_waitcnt vmcnt(0)" ::: "memory");
  __builtin_amdgcn_sched_barrier(0);
  __builtin_amdgcn_s_barrier();
  __builtin_amdgcn_sched_barrier(0);
  compute(cb);

  // epilogue: C/D layout (m89-verified, dtype-independent):
  // col = lane&15, row = (lane>>4)*4 + reg
  const float sc = params[2];
  const int crow = m0 + wm * 64 + q4 * 4;
  const int ccol = n0 + wn * 64 + r16;
#pragma unroll
  for (int i = 0; i < 4; ++i)
#pragma unroll
    for (int j = 0; j < 4; ++j)
#pragma unroll
      for (int r = 0; r < 4; ++r)
        C[(size_t)(crow + i * 16 + r) * N + (ccol + j * 16)] = (float)acc[i][j][r] * sc;
}

// ---------------- launch ----------------

extern "C" void kernel_launch(void* const* d_in, const int* in_sizes, int n_in,
                              void* d_out, int out_size, void* d_ws, size_t ws_size,
                              hipStream_t stream) {
  const float* x = (const float*)d_in[0];
  const float* w = (const float*)d_in[1];
  float* out = (float*)d_out;
  char* ws = (char*)d_ws;

  unsigned* gamma_bits = (unsigned*)ws;            // 4 B
  float*    params     = (float*)(ws + 16);        // 3 floats
  float*    partials   = (float*)(ws + 256);       // 2048 floats
  char*     xq = ws + 16384;                       // 33,554,432 B
  char*     wq = ws + 16384 + (size_t)NX;          // 67,108,864 B

  hipMemsetAsync(ws, 0, 256, stream);  // zero gamma accumulator each call

  reduce_absmax_kernel<<<NPART, 256, 0, stream>>>(x, gamma_bits, (int)(NX / 4));
  reduce_abssum_kernel<<<NPART, 256, 0, stream>>>(w, partials, (int)(NW / 4));
  finalize_kernel<<<1, 256, 0, stream>>>(gamma_bits, partials, params);
  quant_x_kernel<<<2048, 256, 0, stream>>>(x, xq, params, (int)(NX / 16));
  quant_w_kernel<<<2048, 256, 0, stream>>>(w, wq, params, (int)(NW / 16));

  gemm_kernel<<<4096, 512, 0, stream>>>(xq, wq, out, params);
}